// Round 9
// baseline (671.675 us; speedup 1.0000x reference)
//
#include <hip/hip_runtime.h>

#define DD 128
#define NL 4
#define BN_EPS 1e-5f
#define WSTRIDE 16384   // 128*128 bf16 elements per packed matrix
#define CAP 10240       // per-bucket edge capacity
#define CHUNK 8192      // edges per k_scatter block
#define NST 512         // k_stats3 grid
#define SBUK 16         // stat atomic buckets (contention = nblocks/SBUK)
#define SUBB 32         // src sub-buckets per row (sort granularity 2048 nodes)
#define SSHIFT 11       // sub = src >> SSHIFT

typedef __attribute__((ext_vector_type(8))) short short8;
typedef __attribute__((ext_vector_type(4))) float f32x4;

__device__ inline float bf2f(unsigned short u) {
  unsigned int x = ((unsigned int)u) << 16;
  return __builtin_bit_cast(float, x);
}
__device__ inline unsigned short f2bf(float f) {
  unsigned int u = __builtin_bit_cast(unsigned int, f);
  unsigned int r = (u + 0x7fffu + ((u >> 16) & 1u)) >> 16;
  return (unsigned short)r;
}

// sum SBUK bucketed partials for entry tid (tid < 256 range covers sum+sumsq)
__device__ inline float bucket_sum(const float* __restrict__ S, int tid) {
  float a = 0.f;
#pragma unroll
  for (int b = 0; b < SBUK; ++b) a += S[b * 256 + tid];
  return a;
}

// ---------------- bucketed CSR build ----------------

__global__ __launch_bounds__(256) void k_scatter(const int* __restrict__ src,
                                                 const int* __restrict__ dst,
                                                 int* __restrict__ fill,
                                                 int* __restrict__ ebuf, int E) {
  __shared__ int hist[256], blkbase[256], cnt2[256];
  int tid = threadIdx.x;
  hist[tid] = 0;
  cnt2[tid] = 0;
  __syncthreads();
  int base = blockIdx.x * CHUNK;
  int cnt = min(CHUNK, E - base);
  for (int i = tid; i < cnt; i += 256) atomicAdd(&hist[dst[base + i] >> 8], 1);
  __syncthreads();
  int h = hist[tid];
  if (h > 0) blkbase[tid] = atomicAdd(&fill[tid], h);
  __syncthreads();
  for (int i = tid; i < cnt; i += 256) {
    int d = dst[base + i];
    int b = d >> 8;
    int off = blkbase[b] + atomicAdd(&cnt2[b], 1);
    if (off < CAP) ebuf[b * CAP + off] = ((d & 255) << 16) | src[base + i];
  }
}

// counting sort over keys (row, src>>SSHIFT): one count scan, in-LDS prefix,
// one distribute scan. Keeps rows contiguous and approx src-sorted.

__global__ __launch_bounds__(256) void k_csr(const int* __restrict__ fill,
                                             const int* __restrict__ ebuf,
                                             unsigned short* __restrict__ perm,
                                             int* __restrict__ row_beg,
                                             int* __restrict__ row_end, int n) {
  __shared__ int hist[SUBB * 256];  // 32KB
  __shared__ int csum[256];
  int tid = threadIdx.x;
  int b = blockIdx.x;
  for (int i = tid; i < SUBB * 256; i += 256) hist[i] = 0;
  __syncthreads();
  int cnt = min(fill[b], CAP);
  int base = b * CAP;
  for (int i = tid; i < cnt; i += 256) {
    int e = ebuf[base + i];
    int key = ((e & 0xFFFF) >> SSHIFT) * 256 + (e >> 16);
    atomicAdd(&hist[key], 1);
  }
  __syncthreads();
  int my[SUBB];
  int sum = 0;
#pragma unroll
  for (int k = 0; k < SUBB; ++k) {
    my[k] = hist[k * 256 + tid];
    sum += my[k];
  }
  csum[tid] = sum;
  __syncthreads();
  for (int off = 1; off < 256; off <<= 1) {
    int x = (tid >= off) ? csum[tid - off] : 0;
    __syncthreads();
    csum[tid] += x;
    __syncthreads();
  }
  int excl = csum[tid] - sum;
  int run = excl;
#pragma unroll
  for (int k = 0; k < SUBB; ++k) {
    hist[k * 256 + tid] = run;
    run += my[k];
  }
  int node = b * 256 + tid;
  if (node < n) {
    row_beg[node] = base + excl;
    row_end[node] = base + excl + sum;
  }
  __syncthreads();
  for (int i = tid; i < cnt; i += 256) {
    int e = ebuf[base + i];
    int key = ((e & 0xFFFF) >> SSHIFT) * 256 + (e >> 16);
    int pos = atomicAdd(&hist[key], 1);
    perm[base + pos] = (unsigned short)(e & 0xFFFF);
  }
}

// ---------------- W pre-pack ----------------

__global__ void k_packW(const float* __restrict__ W, unsigned short* __restrict__ out,
                        int nmat) {
  int idx = blockIdx.x * 256 + threadIdx.x;
  int m = idx >> 14;
  if (m >= nmat) return;
  int o = idx & (WSTRIDE - 1);
  int frag = o >> 9;
  int l = (o >> 3) & 63;
  int j = o & 7;
  int t = frag >> 2, s = frag & 3;
  int k = s * 32 + ((l >> 4) << 3) + j;
  int n = (t << 4) + (l & 15);
  out[(size_t)m * WSTRIDE + o] = f2bf(W[(size_t)m * (DD * DD) + k * DD + n]);
}

// ------ GIN aggregation, feature-quartered with CHUNK-SEPARATED arrays -------
// hbs/xbs are 4 separate [n][32] bf16 arrays (3.2MB each, fits per-XCD 4MiB L2
// with no cache-line sharing between chunks — fixes round-3's line-split bug).
// Phase q = bid/nbq; 12500 blocks total (16 nodes/block, 1 node per wave-pass,
// 4 sequential nodes per wave). 16 subwaves x 4 lanes x 16B = one 64B
// chunk-row per edge; 2-deep unroll (deg~32 = 16 slots x 2).

__global__ __launch_bounds__(256) void k_aggq2(
    const unsigned short* __restrict__ hbs, const int* __restrict__ row_beg,
    const int* __restrict__ row_end, const unsigned short* __restrict__ perm,
    const float* __restrict__ epsv, int layer, unsigned short* __restrict__ xbs,
    int n, int nbq) {
  int bid = blockIdx.x;
  int q = bid / nbq;
  int nblk = bid - q * nbq;
  int wave = threadIdx.x >> 6, lane = threadIdx.x & 63;
  int sub = lane >> 2;  // 0..15 edge slots
  int c4 = lane & 3;    // 16B slice of the 64B chunk-row
  const unsigned short* hq = hbs + (size_t)q * n * 32 + c4 * 8;
  unsigned short* xq = xbs + (size_t)q * n * 32 + c4 * 8;
  float ep = 1.0f + epsv[layer];
  int wv0 = nblk * 16 + wave * 4;
  for (int k = 0; k < 4; ++k) {
    int wv = wv0 + k;
    if (wv >= n) break;
    int beg = row_beg[wv], end = row_end[wv];
    float acc[8] = {0.f, 0.f, 0.f, 0.f, 0.f, 0.f, 0.f, 0.f};
    int e = beg + sub;
    for (; e + 16 < end; e += 32) {
      int s0 = perm[e];
      int s1 = perm[e + 16];
      short8 v0 = *(const short8*)(hq + (size_t)s0 * 32);
      short8 v1 = *(const short8*)(hq + (size_t)s1 * 32);
#pragma unroll
      for (int j = 0; j < 8; ++j)
        acc[j] += bf2f((unsigned short)v0[j]) + bf2f((unsigned short)v1[j]);
    }
    if (e < end) {
      int s0 = perm[e];
      short8 v0 = *(const short8*)(hq + (size_t)s0 * 32);
#pragma unroll
      for (int j = 0; j < 8; ++j) acc[j] += bf2f((unsigned short)v0[j]);
    }
#pragma unroll
    for (int j = 0; j < 8; ++j) {
      acc[j] += __shfl_xor(acc[j], 4);
      acc[j] += __shfl_xor(acc[j], 8);
      acc[j] += __shfl_xor(acc[j], 16);
      acc[j] += __shfl_xor(acc[j], 32);
    }
    if (sub == 0) {
      short8 hv = *(const short8*)(hq + (size_t)wv * 32);
      short8 o;
#pragma unroll
      for (int j = 0; j < 8; ++j)
        o[j] = (short)f2bf(fmaf(ep, bf2f((unsigned short)hv[j]), acc[j]));
      *(short8*)(xq + (size_t)wv * 32) = o;
    }
  }
}

// ---------------- bf16 MFMA GEMM [nrows,128] x [128,128] + bias ----------------
// W staged in LDS. PRE: relu-bn on A-load. STATS: bucketed atomics.
// IN_SPLIT: A read from 4 chunk-separated [nrows][32] bf16 arrays (chunk = s).
// OUT_SPLIT: bf16 output written to chunk-separated arrays (chunk = col>>5).

template <bool PRE, bool STATS, bool IN_F32, bool OUT_BF16, bool OUT_F32,
          bool IN_SPLIT, bool OUT_SPLIT>
__global__ __launch_bounds__(256) void k_gemm_mfma(
    const void* __restrict__ Xv, const unsigned short* __restrict__ Wb,
    const float* __restrict__ bias, const float* __restrict__ statsPre,
    const float* __restrict__ gPre, const float* __restrict__ bPre,
    unsigned short* __restrict__ Yb, float* __restrict__ Yf,
    float* __restrict__ Sout, int nrows, float inv_n) {
  __shared__ short8 Wl[2048];      // 32KB packed W
  __shared__ float red[4][2][DD];  // [wave][sum/sumsq][col]
  __shared__ float s_sc[DD], s_sh[DD];
  int tid = threadIdx.x;
  int wave = tid >> 6, lane = tid & 63;
  int quad = lane >> 4, n16 = lane & 15;
  int m0 = blockIdx.x * 64 + wave * 16;
  int rowA = m0 + n16;

  const short8* W8 = (const short8*)Wb;
#pragma unroll
  for (int i = 0; i < 8; ++i) Wl[i * 256 + tid] = W8[i * 256 + tid];

  if (PRE) {
    if (tid < DD) {
      float mu = bucket_sum(statsPre, tid) * inv_n;
      float var = bucket_sum(statsPre, DD + tid) * inv_n - mu * mu;
      float sc = gPre[tid] * rsqrtf(var + BN_EPS);
      s_sc[tid] = sc;
      s_sh[tid] = fmaf(-mu, sc, bPre[tid]);
    }
  }
  __syncthreads();

  f32x4 acc[8];
#pragma unroll
  for (int t = 0; t < 8; ++t) acc[t] = (f32x4){0.f, 0.f, 0.f, 0.f};

#pragma unroll
  for (int s = 0; s < 4; ++s) {
    int kbase = s * 32 + quad * 8;
    short8 a = {0, 0, 0, 0, 0, 0, 0, 0};
    if (rowA < nrows) {
      if (IN_F32) {
        const float* xp = (const float*)Xv + (size_t)rowA * DD + kbase;
        float4 v0 = ((const float4*)xp)[0];
        float4 v1 = ((const float4*)xp)[1];
        a[0] = (short)f2bf(v0.x); a[1] = (short)f2bf(v0.y);
        a[2] = (short)f2bf(v0.z); a[3] = (short)f2bf(v0.w);
        a[4] = (short)f2bf(v1.x); a[5] = (short)f2bf(v1.y);
        a[6] = (short)f2bf(v1.z); a[7] = (short)f2bf(v1.w);
      } else if (IN_SPLIT) {
        const unsigned short* Xs = (const unsigned short*)Xv;
        a = *(const short8*)(Xs + (size_t)s * nrows * 32 + (size_t)rowA * 32 +
                             quad * 8);
      } else {
        a = *(const short8*)((const unsigned short*)Xv + (size_t)rowA * DD + kbase);
        if (PRE) {
#pragma unroll
          for (int j = 0; j < 8; ++j) {
            float v = bf2f((unsigned short)a[j]);
            v = fmaxf(fmaf(v, s_sc[kbase + j], s_sh[kbase + j]), 0.f);
            a[j] = (short)f2bf(v);
          }
        }
      }
    }
#pragma unroll
    for (int t = 0; t < 8; ++t) {
      short8 b = Wl[(t * 4 + s) * 64 + lane];
      acc[t] = __builtin_amdgcn_mfma_f32_16x16x32_bf16(a, b, acc[t], 0, 0, 0);
    }
  }

#pragma unroll
  for (int t = 0; t < 8; ++t) {
    int col = t * 16 + n16;
    float bv = bias[col];
    float s_c = 0.f, q_c = 0.f;
#pragma unroll
    for (int r = 0; r < 4; ++r) {
      int row = m0 + quad * 4 + r;
      if (row < nrows) {
        float v = acc[t][r] + bv;
        if (OUT_BF16) {
          if (OUT_SPLIT)
            Yb[(size_t)(col >> 5) * nrows * 32 + (size_t)row * 32 + (col & 31)] =
                f2bf(v);
          else
            Yb[(size_t)row * DD + col] = f2bf(v);
        }
        if (OUT_F32) Yf[(size_t)row * DD + col] = v;
        if (STATS) { s_c += v; q_c += v * v; }
      }
    }
    if (STATS) {
      s_c += __shfl_xor(s_c, 16);
      q_c += __shfl_xor(q_c, 16);
      s_c += __shfl_xor(s_c, 32);
      q_c += __shfl_xor(q_c, 32);
      if (quad == 0) {  // lanes 0..15: one writer per (wave,col)
        red[wave][0][col] = s_c;
        red[wave][1][col] = q_c;
      }
    }
  }
  if (STATS) {
    __syncthreads();
    if (tid < DD) {
      float s4 = red[0][0][tid] + red[1][0][tid] + red[2][0][tid] + red[3][0][tid];
      float q4 = red[0][1][tid] + red[1][1][tid] + red[2][1][tid] + red[3][1][tid];
      float* bkt = Sout + (blockIdx.x & (SBUK - 1)) * 256;
      atomicAdd(&bkt[tid], s4);
      atomicAdd(&bkt[DD + tid], q4);
    }
  }
}

// ------- stats of a = relu(bn2(z)), z bf16 normal layout; bucketed atomics -------

__global__ __launch_bounds__(256) void k_stats3(const unsigned short* __restrict__ Z,
                                                const float* __restrict__ stats2,
                                                const float* __restrict__ g2,
                                                const float* __restrict__ b2v,
                                                float* __restrict__ Sout, int n8,
                                                float inv_n) {
  __shared__ float wred[4][2][DD];
  __shared__ float s_sc[DD], s_sh[DD];
  int tid = threadIdx.x;
  if (tid < DD) {
    float mu = bucket_sum(stats2, tid) * inv_n;
    float var = bucket_sum(stats2, DD + tid) * inv_n - mu * mu;
    float sc = g2[tid] * rsqrtf(var + BN_EPS);
    s_sc[tid] = sc;
    s_sh[tid] = fmaf(-mu, sc, b2v[tid]);
  }
  __syncthreads();
  int c8 = tid & 15;
  int wave = tid >> 6, lane = tid & 63;
  float sc[8], sh[8];
#pragma unroll
  for (int j = 0; j < 8; ++j) { sc[j] = s_sc[c8 * 8 + j]; sh[j] = s_sh[c8 * 8 + j]; }
  float s[8] = {0, 0, 0, 0, 0, 0, 0, 0};
  float q[8] = {0, 0, 0, 0, 0, 0, 0, 0};
  for (int idx = blockIdx.x * 256 + tid; idx < n8; idx += gridDim.x * 256) {
    short8 z = ((const short8*)Z)[idx];
#pragma unroll
    for (int j = 0; j < 8; ++j) {
      float a = fmaxf(fmaf(bf2f((unsigned short)z[j]), sc[j], sh[j]), 0.f);
      s[j] += a;
      q[j] += a * a;
    }
  }
#pragma unroll
  for (int j = 0; j < 8; ++j) {  // combine lanes with equal c8 (xor 16, 32)
    s[j] += __shfl_xor(s[j], 16);
    q[j] += __shfl_xor(q[j], 16);
    s[j] += __shfl_xor(s[j], 32);
    q[j] += __shfl_xor(q[j], 32);
  }
  if (lane < 16) {
#pragma unroll
    for (int j = 0; j < 8; ++j) {
      wred[wave][0][lane * 8 + j] = s[j];
      wred[wave][1][lane * 8 + j] = q[j];
    }
  }
  __syncthreads();
  if (tid < DD) {
    float s4 = wred[0][0][tid] + wred[1][0][tid] + wred[2][0][tid] + wred[3][0][tid];
    float q4 = wred[0][1][tid] + wred[1][1][tid] + wred[2][1][tid] + wred[3][1][tid];
    float* bkt = Sout + (blockIdx.x & (SBUK - 1)) * 256;
    atomicAdd(&bkt[tid], s4);
    atomicAdd(&bkt[DD + tid], q4);
  }
}

// ------- final: h += relu(bn3(relu(bn2(z)))); writes H (normal) + hb (split) -------

__global__ __launch_bounds__(256) void k_final(
    const unsigned short* __restrict__ Z, const float* __restrict__ stats2,
    const float* __restrict__ g2, const float* __restrict__ b2v,
    const float* __restrict__ stats3, const float* __restrict__ g3,
    const float* __restrict__ b3v, float* __restrict__ H,
    unsigned short* __restrict__ hbs, int n8, int nn, float inv_n) {
  __shared__ float s2l[DD], h2l[DD], s3l[DD], h3l[DD];
  int tid = threadIdx.x;
  if (tid < DD) {
    float mu = bucket_sum(stats2, tid) * inv_n;
    float var = bucket_sum(stats2, DD + tid) * inv_n - mu * mu;
    float sc = g2[tid] * rsqrtf(var + BN_EPS);
    s2l[tid] = sc;
    h2l[tid] = fmaf(-mu, sc, b2v[tid]);
    mu = bucket_sum(stats3, tid) * inv_n;
    var = bucket_sum(stats3, DD + tid) * inv_n - mu * mu;
    sc = g3[tid] * rsqrtf(var + BN_EPS);
    s3l[tid] = sc;
    h3l[tid] = fmaf(-mu, sc, b3v[tid]);
  }
  __syncthreads();
  int c8 = tid & 15;
  float s2[8], h2[8], s3[8], h3[8];
#pragma unroll
  for (int j = 0; j < 8; ++j) {
    s2[j] = s2l[c8 * 8 + j]; h2[j] = h2l[c8 * 8 + j];
    s3[j] = s3l[c8 * 8 + j]; h3[j] = h3l[c8 * 8 + j];
  }
  // split-mirror write target: chunk c8>>2, in-chunk 16B slot (c8&3)*8
  unsigned short* hq = hbs + (size_t)(c8 >> 2) * nn * 32 + (c8 & 3) * 8;
  for (int idx = blockIdx.x * 256 + tid; idx < n8; idx += gridDim.x * 256) {
    short8 z = ((const short8*)Z)[idx];
    float4 hv0 = ((const float4*)H)[idx * 2];
    float4 hv1 = ((const float4*)H)[idx * 2 + 1];
    float hv[8] = {hv0.x, hv0.y, hv0.z, hv0.w, hv1.x, hv1.y, hv1.z, hv1.w};
    float o[8];
    short8 ob;
#pragma unroll
    for (int j = 0; j < 8; ++j) {
      float a = fmaxf(fmaf(bf2f((unsigned short)z[j]), s2[j], h2[j]), 0.f);
      o[j] = hv[j] + fmaxf(fmaf(a, s3[j], h3[j]), 0.f);
      ob[j] = (short)f2bf(o[j]);
    }
    ((float4*)H)[idx * 2] = make_float4(o[0], o[1], o[2], o[3]);
    ((float4*)H)[idx * 2 + 1] = make_float4(o[4], o[5], o[6], o[7]);
    int node = idx >> 4;
    *(short8*)(hq + (size_t)node * 32) = ob;
  }
}

// ---------------- launch ----------------

extern "C" void kernel_launch(void* const* d_in, const int* in_sizes, int n_in,
                              void* d_out, int out_size, void* d_ws, size_t ws_size,
                              hipStream_t stream) {
  const float* h_in = (const float*)d_in[0];
  const int* src = (const int*)d_in[1];
  const int* dst = (const int*)d_in[2];
  const float* W_emb = (const float*)d_in[3];
  const float* b_emb = (const float*)d_in[4];
  const float* epsv = (const float*)d_in[5];
  const float* W1 = (const float*)d_in[6];
  const float* b1 = (const float*)d_in[7];
  const float* g1 = (const float*)d_in[8];
  const float* be1 = (const float*)d_in[9];
  const float* W2 = (const float*)d_in[10];
  const float* b2 = (const float*)d_in[11];
  const float* ga = (const float*)d_in[12];
  const float* ba = (const float*)d_in[13];
  const float* gl = (const float*)d_in[14];
  const float* bl = (const float*)d_in[15];

  const int Nn = in_sizes[0] / DD;  // 50000
  const int E = in_sizes[1];        // 1600000
  const int nbuck = (Nn + 255) >> 8;
  const int gb = (Nn + 63) / 64;
  const int nbq = (Nn + 15) / 16;   // node-blocks per feature-quarter phase

  char* ws = (char*)d_ws;
  size_t off = 0;
  auto alloc = [&](size_t bytes) -> void* {
    off = (off + 255) & ~(size_t)255;
    void* p = ws + off;
    off += bytes;
    return p;
  };
  int* ebuf = (int*)alloc((size_t)nbuck * CAP * 4);
  unsigned short* perm = (unsigned short*)alloc((size_t)nbuck * CAP * 2);
  // fill[256] + 12 bucketed stats buffers S (3/layer x SBUK x 256), one memset
  const size_t sbytes = (size_t)12 * SBUK * 256 * 4;
  int* fill = (int*)alloc(256 * 4 + sbytes);
  float* Sall = (float*)(fill + 256);
  int* row_beg = (int*)alloc((size_t)Nn * 4);
  int* row_end = (int*)alloc((size_t)Nn * 4);
  unsigned short* Wb = (unsigned short*)alloc((size_t)9 * WSTRIDE * 2);
  unsigned short* hbs = (unsigned short*)alloc((size_t)Nn * DD * 2);  // split [4][Nn][32]
  unsigned short* xbs = (unsigned short*)alloc((size_t)Nn * DD * 2);  // split [4][Nn][32]
  unsigned short* yb = (unsigned short*)alloc((size_t)Nn * DD * 2);   // normal
  unsigned short* zb = (unsigned short*)alloc((size_t)Nn * DD * 2);   // normal
  float* h = (float*)d_out;  // fp32 h chain lives in d_out

  hipMemsetAsync(fill, 0, 256 * 4 + sbytes, stream);

  // CSR build (bucketed, rows approx src-sorted via counting sort)
  int nblk1 = (E + CHUNK - 1) / CHUNK;
  k_scatter<<<nblk1, 256, 0, stream>>>(src, dst, fill, ebuf, E);
  k_csr<<<nbuck, 256, 0, stream>>>(fill, ebuf, perm, row_beg, row_end, Nn);

  // W pre-pack (bf16, B-fragment order)
  k_packW<<<(1 * WSTRIDE + 255) / 256, 256, 0, stream>>>(W_emb, Wb, 1);
  k_packW<<<(4 * WSTRIDE + 255) / 256, 256, 0, stream>>>(W1, Wb + WSTRIDE, 4);
  k_packW<<<(4 * WSTRIDE + 255) / 256, 256, 0, stream>>>(W2, Wb + (size_t)WSTRIDE * 5, 4);

  float inv_n = 1.0f / (float)Nn;
  int n8 = Nn * DD / 8;

  // embed: h = h_in @ W_emb + b_emb (fp32 h into d_out + split bf16 mirror hbs)
  k_gemm_mfma<false, false, true, true, true, false, true><<<gb, 256, 0, stream>>>(
      h_in, Wb, b_emb, nullptr, nullptr, nullptr, hbs, h, nullptr, Nn, inv_n);

  for (int i = 0; i < NL; ++i) {
    float* S1 = Sall + (size_t)i * 3 * SBUK * 256;
    float* S2 = S1 + SBUK * 256;
    float* S3 = S2 + SBUK * 256;
    k_aggq2<<<4 * nbq, 256, 0, stream>>>(hbs, row_beg, row_end, perm, epsv, i, xbs,
                                         Nn, nbq);
    k_gemm_mfma<false, true, false, true, false, true, false><<<gb, 256, 0, stream>>>(
        xbs, Wb + (size_t)WSTRIDE * (1 + i), b1 + i * DD, nullptr, nullptr, nullptr,
        yb, nullptr, S1, Nn, inv_n);
    k_gemm_mfma<true, true, false, true, false, false, false><<<gb, 256, 0, stream>>>(
        yb, Wb + (size_t)WSTRIDE * (5 + i), b2 + i * DD, S1, g1 + i * DD, be1 + i * DD,
        zb, nullptr, S2, Nn, inv_n);
    k_stats3<<<NST, 256, 0, stream>>>(zb, S2, ga + i * DD, ba + i * DD, S3, n8,
                                      inv_n);
    k_final<<<2048, 256, 0, stream>>>(zb, S2, ga + i * DD, ba + i * DD, S3, gl + i * DD,
                                      bl + i * DD, h, hbs, n8, Nn, inv_n);
  }
}

// Round 10
// 583.686 us; speedup vs baseline: 1.1507x; 1.1507x over previous
//
#include <hip/hip_runtime.h>

#define DD 128
#define NL 4
#define BN_EPS 1e-5f
#define WSTRIDE 16384   // 128*128 bf16 elements per packed matrix
#define CAP 10240       // per-bucket edge capacity
#define CHUNK 8192      // edges per k_scatter block
#define NST 512         // k_stats3 grid
#define SBUK 16         // stat atomic buckets (contention = nblocks/SBUK)

typedef __attribute__((ext_vector_type(8))) short short8;
typedef __attribute__((ext_vector_type(4))) float f32x4;

__device__ inline float bf2f(unsigned short u) {
  unsigned int x = ((unsigned int)u) << 16;
  return __builtin_bit_cast(float, x);
}
__device__ inline unsigned short f2bf(float f) {
  unsigned int u = __builtin_bit_cast(unsigned int, f);
  unsigned int r = (u + 0x7fffu + ((u >> 16) & 1u)) >> 16;
  return (unsigned short)r;
}

// sum SBUK bucketed partials for entry tid (tid < 256 range covers sum+sumsq)
__device__ inline float bucket_sum(const float* __restrict__ S, int tid) {
  float a = 0.f;
#pragma unroll
  for (int b = 0; b < SBUK; ++b) a += S[b * 256 + tid];
  return a;
}

// ---------------- bucketed CSR build ----------------

__global__ __launch_bounds__(256) void k_scatter(const int* __restrict__ src,
                                                 const int* __restrict__ dst,
                                                 int* __restrict__ fill,
                                                 int* __restrict__ ebuf, int E) {
  __shared__ int hist[256], blkbase[256], cnt2[256];
  int tid = threadIdx.x;
  hist[tid] = 0;
  cnt2[tid] = 0;
  __syncthreads();
  int base = blockIdx.x * CHUNK;
  int cnt = min(CHUNK, E - base);
  for (int i = tid; i < cnt; i += 256) atomicAdd(&hist[dst[base + i] >> 8], 1);
  __syncthreads();
  int h = hist[tid];
  if (h > 0) blkbase[tid] = atomicAdd(&fill[tid], h);
  __syncthreads();
  for (int i = tid; i < cnt; i += 256) {
    int d = dst[base + i];
    int b = d >> 8;
    int off = blkbase[b] + atomicAdd(&cnt2[b], 1);
    if (off < CAP) ebuf[b * CAP + off] = ((d & 255) << 16) | src[base + i];
  }
}

// simple per-row distribute (src-sort measured null for locality -> removed)

__global__ __launch_bounds__(256) void k_csr(const int* __restrict__ fill,
                                             const int* __restrict__ ebuf,
                                             unsigned short* __restrict__ perm,
                                             int* __restrict__ row_beg,
                                             int* __restrict__ row_end, int n) {
  __shared__ int ncnt[256], lstart[256], cnt2[256], s[256];
  int tid = threadIdx.x;
  int b = blockIdx.x;
  ncnt[tid] = 0;
  cnt2[tid] = 0;
  __syncthreads();
  int cnt = min(fill[b], CAP);
  int base = b * CAP;
  for (int i = tid; i < cnt; i += 256) atomicAdd(&ncnt[ebuf[base + i] >> 16], 1);
  __syncthreads();
  int v = ncnt[tid];
  s[tid] = v;
  __syncthreads();
  for (int off = 1; off < 256; off <<= 1) {
    int x = (tid >= off) ? s[tid - off] : 0;
    __syncthreads();
    s[tid] += x;
    __syncthreads();
  }
  int st = s[tid] - v;
  lstart[tid] = st;
  int node = b * 256 + tid;
  if (node < n) {
    row_beg[node] = base + st;
    row_end[node] = base + st + v;
  }
  __syncthreads();
  for (int i = tid; i < cnt; i += 256) {
    int e = ebuf[base + i];
    int l = e >> 16;
    int pos = lstart[l] + atomicAdd(&cnt2[l], 1);
    perm[base + pos] = (unsigned short)(e & 0xFFFF);
  }
}

// ---------------- W pre-pack ----------------

__global__ void k_packW(const float* __restrict__ W, unsigned short* __restrict__ out,
                        int nmat) {
  int idx = blockIdx.x * 256 + threadIdx.x;
  int m = idx >> 14;
  if (m >= nmat) return;
  int o = idx & (WSTRIDE - 1);
  int frag = o >> 9;
  int l = (o >> 3) & 63;
  int j = o & 7;
  int t = frag >> 2, s = frag & 3;
  int k = s * 32 + ((l >> 4) << 3) + j;
  int n = (t << 4) + (l & 15);
  out[(size_t)m * WSTRIDE + o] = f2bf(W[(size_t)m * (DD * DD) + k * DD + n]);
}

// ---------------- GIN aggregation (pull, bucketed CSR, bf16 rows) ----------------
// Round-2 structure (measured floor 48.8us): 1 node/wave, 12500 blocks,
// 8-deep unrolled gather + 4/2/1 geometric tail.

__global__ __launch_bounds__(256) void k_aggregate(
    const unsigned short* __restrict__ hb, const int* __restrict__ row_beg,
    const int* __restrict__ row_end, const unsigned short* __restrict__ perm,
    const float* __restrict__ epsv, int layer, unsigned short* __restrict__ xout,
    int n) {
  int wv = (blockIdx.x * 256 + threadIdx.x) >> 6;
  if (wv >= n) return;
  int lane = threadIdx.x & 63;
  int sub = lane >> 4;
  int c8 = lane & 15;
  int beg = row_beg[wv], end = row_end[wv];
  float acc[8] = {0.f, 0.f, 0.f, 0.f, 0.f, 0.f, 0.f, 0.f};
  const unsigned short* hbc = hb + c8 * 8;
  int e = beg + sub;
  for (; e + 28 < end; e += 32) {
    int s0 = perm[e];
    int s1 = perm[e + 4];
    int s2 = perm[e + 8];
    int s3 = perm[e + 12];
    int s4 = perm[e + 16];
    int s5 = perm[e + 20];
    int s6 = perm[e + 24];
    int s7 = perm[e + 28];
    short8 v0 = *(const short8*)(hbc + (size_t)s0 * DD);
    short8 v1 = *(const short8*)(hbc + (size_t)s1 * DD);
    short8 v2 = *(const short8*)(hbc + (size_t)s2 * DD);
    short8 v3 = *(const short8*)(hbc + (size_t)s3 * DD);
    short8 v4 = *(const short8*)(hbc + (size_t)s4 * DD);
    short8 v5 = *(const short8*)(hbc + (size_t)s5 * DD);
    short8 v6 = *(const short8*)(hbc + (size_t)s6 * DD);
    short8 v7 = *(const short8*)(hbc + (size_t)s7 * DD);
#pragma unroll
    for (int j = 0; j < 8; ++j) {
      float t0 = bf2f((unsigned short)v0[j]) + bf2f((unsigned short)v1[j]);
      float t1 = bf2f((unsigned short)v2[j]) + bf2f((unsigned short)v3[j]);
      float t2 = bf2f((unsigned short)v4[j]) + bf2f((unsigned short)v5[j]);
      float t3 = bf2f((unsigned short)v6[j]) + bf2f((unsigned short)v7[j]);
      acc[j] += (t0 + t1) + (t2 + t3);
    }
  }
  if (e + 12 < end) {
    int s0 = perm[e];
    int s1 = perm[e + 4];
    int s2 = perm[e + 8];
    int s3 = perm[e + 12];
    short8 v0 = *(const short8*)(hbc + (size_t)s0 * DD);
    short8 v1 = *(const short8*)(hbc + (size_t)s1 * DD);
    short8 v2 = *(const short8*)(hbc + (size_t)s2 * DD);
    short8 v3 = *(const short8*)(hbc + (size_t)s3 * DD);
#pragma unroll
    for (int j = 0; j < 8; ++j) {
      acc[j] += (bf2f((unsigned short)v0[j]) + bf2f((unsigned short)v1[j])) +
                (bf2f((unsigned short)v2[j]) + bf2f((unsigned short)v3[j]));
    }
    e += 16;
  }
  if (e + 4 < end) {
    int s0 = perm[e];
    int s1 = perm[e + 4];
    short8 v0 = *(const short8*)(hbc + (size_t)s0 * DD);
    short8 v1 = *(const short8*)(hbc + (size_t)s1 * DD);
#pragma unroll
    for (int j = 0; j < 8; ++j)
      acc[j] += bf2f((unsigned short)v0[j]) + bf2f((unsigned short)v1[j]);
    e += 8;
  }
  if (e < end) {
    int s0 = perm[e];
    short8 v0 = *(const short8*)(hbc + (size_t)s0 * DD);
#pragma unroll
    for (int j = 0; j < 8; ++j) acc[j] += bf2f((unsigned short)v0[j]);
  }
#pragma unroll
  for (int j = 0; j < 8; ++j) {
    acc[j] += __shfl_xor(acc[j], 16);
    acc[j] += __shfl_xor(acc[j], 32);
  }
  if (sub == 0) {
    float ep = 1.0f + epsv[layer];
    short8 hv = *(const short8*)(hb + (size_t)wv * DD + c8 * 8);
    short8 o;
#pragma unroll
    for (int j = 0; j < 8; ++j)
      o[j] = (short)f2bf(fmaf(ep, bf2f((unsigned short)hv[j]), acc[j]));
    *(short8*)(xout + (size_t)wv * DD + c8 * 8) = o;
  }
}

// ---------------- bf16 MFMA GEMM [nrows,128] x [128,128] + bias ----------------
// 128-ROW BLOCKS: 2 row-groups (offset 0 and 64) per wave amortize the 32KB
// W LDS stage + barrier over 2x the MFMA work (391 blocks, was 782).
// PRE: relu(x*sc+sh) on A-load; STATS: bucketed atomics.

template <bool PRE, bool STATS, bool IN_F32, bool OUT_BF16, bool OUT_F32>
__global__ __launch_bounds__(256) void k_gemm_mfma(
    const void* __restrict__ Xv, const unsigned short* __restrict__ Wb,
    const float* __restrict__ bias, const float* __restrict__ statsPre,
    const float* __restrict__ gPre, const float* __restrict__ bPre,
    unsigned short* __restrict__ Yb, float* __restrict__ Yf,
    float* __restrict__ Sout, int nrows, float inv_n) {
  __shared__ short8 Wl[2048];      // 32KB packed W
  __shared__ float red[4][2][DD];  // [wave][sum/sumsq][col]
  __shared__ float s_sc[DD], s_sh[DD];
  int tid = threadIdx.x;
  int wave = tid >> 6, lane = tid & 63;
  int quad = lane >> 4, n16 = lane & 15;
  int m0 = blockIdx.x * 128 + wave * 16;  // row-group 0; group 1 at +64

  const short8* W8 = (const short8*)Wb;
#pragma unroll
  for (int i = 0; i < 8; ++i) Wl[i * 256 + tid] = W8[i * 256 + tid];

  if (PRE) {
    if (tid < DD) {
      float mu = bucket_sum(statsPre, tid) * inv_n;
      float var = bucket_sum(statsPre, DD + tid) * inv_n - mu * mu;
      float sc = gPre[tid] * rsqrtf(var + BN_EPS);
      s_sc[tid] = sc;
      s_sh[tid] = fmaf(-mu, sc, bPre[tid]);
    }
  }
  __syncthreads();

  f32x4 acc[2][8];
#pragma unroll
  for (int g = 0; g < 2; ++g)
#pragma unroll
    for (int t = 0; t < 8; ++t) acc[g][t] = (f32x4){0.f, 0.f, 0.f, 0.f};

#pragma unroll
  for (int s = 0; s < 4; ++s) {
    int kbase = s * 32 + quad * 8;
    short8 a[2];
#pragma unroll
    for (int g = 0; g < 2; ++g) {
      int rowA = m0 + g * 64 + n16;
      short8 av = {0, 0, 0, 0, 0, 0, 0, 0};
      if (rowA < nrows) {
        if (IN_F32) {
          const float* xp = (const float*)Xv + (size_t)rowA * DD + kbase;
          float4 v0 = ((const float4*)xp)[0];
          float4 v1 = ((const float4*)xp)[1];
          av[0] = (short)f2bf(v0.x); av[1] = (short)f2bf(v0.y);
          av[2] = (short)f2bf(v0.z); av[3] = (short)f2bf(v0.w);
          av[4] = (short)f2bf(v1.x); av[5] = (short)f2bf(v1.y);
          av[6] = (short)f2bf(v1.z); av[7] = (short)f2bf(v1.w);
        } else {
          av = *(const short8*)((const unsigned short*)Xv + (size_t)rowA * DD + kbase);
          if (PRE) {
#pragma unroll
            for (int j = 0; j < 8; ++j) {
              float v = bf2f((unsigned short)av[j]);
              v = fmaxf(fmaf(v, s_sc[kbase + j], s_sh[kbase + j]), 0.f);
              av[j] = (short)f2bf(v);
            }
          }
        }
      }
      a[g] = av;
    }
#pragma unroll
    for (int t = 0; t < 8; ++t) {
      short8 b = Wl[(t * 4 + s) * 64 + lane];
      acc[0][t] = __builtin_amdgcn_mfma_f32_16x16x32_bf16(a[0], b, acc[0][t], 0, 0, 0);
      acc[1][t] = __builtin_amdgcn_mfma_f32_16x16x32_bf16(a[1], b, acc[1][t], 0, 0, 0);
    }
  }

#pragma unroll
  for (int t = 0; t < 8; ++t) {
    int col = t * 16 + n16;
    float bv = bias[col];
    float s_c = 0.f, q_c = 0.f;
#pragma unroll
    for (int g = 0; g < 2; ++g) {
#pragma unroll
      for (int r = 0; r < 4; ++r) {
        int row = m0 + g * 64 + quad * 4 + r;
        if (row < nrows) {
          float v = acc[g][t][r] + bv;
          if (OUT_BF16) Yb[(size_t)row * DD + col] = f2bf(v);
          if (OUT_F32) Yf[(size_t)row * DD + col] = v;
          if (STATS) { s_c += v; q_c += v * v; }
        }
      }
    }
    if (STATS) {
      s_c += __shfl_xor(s_c, 16);
      q_c += __shfl_xor(q_c, 16);
      s_c += __shfl_xor(s_c, 32);
      q_c += __shfl_xor(q_c, 32);
      if (quad == 0) {  // lanes 0..15: one writer per (wave,col)
        red[wave][0][col] = s_c;
        red[wave][1][col] = q_c;
      }
    }
  }
  if (STATS) {
    __syncthreads();
    if (tid < DD) {
      float s4 = red[0][0][tid] + red[1][0][tid] + red[2][0][tid] + red[3][0][tid];
      float q4 = red[0][1][tid] + red[1][1][tid] + red[2][1][tid] + red[3][1][tid];
      float* bkt = Sout + (blockIdx.x & (SBUK - 1)) * 256;
      atomicAdd(&bkt[tid], s4);
      atomicAdd(&bkt[DD + tid], q4);
    }
  }
}

// ------- stats of a = relu(bn2(z)), z bf16; bucketed atomic accumulation -------

__global__ __launch_bounds__(256) void k_stats3(const unsigned short* __restrict__ Z,
                                                const float* __restrict__ stats2,
                                                const float* __restrict__ g2,
                                                const float* __restrict__ b2v,
                                                float* __restrict__ Sout, int n8,
                                                float inv_n) {
  __shared__ float wred[4][2][DD];
  __shared__ float s_sc[DD], s_sh[DD];
  int tid = threadIdx.x;
  if (tid < DD) {
    float mu = bucket_sum(stats2, tid) * inv_n;
    float var = bucket_sum(stats2, DD + tid) * inv_n - mu * mu;
    float sc = g2[tid] * rsqrtf(var + BN_EPS);
    s_sc[tid] = sc;
    s_sh[tid] = fmaf(-mu, sc, b2v[tid]);
  }
  __syncthreads();
  int c8 = tid & 15;
  int wave = tid >> 6, lane = tid & 63;
  float sc[8], sh[8];
#pragma unroll
  for (int j = 0; j < 8; ++j) { sc[j] = s_sc[c8 * 8 + j]; sh[j] = s_sh[c8 * 8 + j]; }
  float s[8] = {0, 0, 0, 0, 0, 0, 0, 0};
  float q[8] = {0, 0, 0, 0, 0, 0, 0, 0};
  for (int idx = blockIdx.x * 256 + tid; idx < n8; idx += gridDim.x * 256) {
    short8 z = ((const short8*)Z)[idx];
#pragma unroll
    for (int j = 0; j < 8; ++j) {
      float a = fmaxf(fmaf(bf2f((unsigned short)z[j]), sc[j], sh[j]), 0.f);
      s[j] += a;
      q[j] += a * a;
    }
  }
#pragma unroll
  for (int j = 0; j < 8; ++j) {  // combine lanes with equal c8 (xor 16, 32)
    s[j] += __shfl_xor(s[j], 16);
    q[j] += __shfl_xor(q[j], 16);
    s[j] += __shfl_xor(s[j], 32);
    q[j] += __shfl_xor(q[j], 32);
  }
  if (lane < 16) {
#pragma unroll
    for (int j = 0; j < 8; ++j) {
      wred[wave][0][lane * 8 + j] = s[j];
      wred[wave][1][lane * 8 + j] = q[j];
    }
  }
  __syncthreads();
  if (tid < DD) {
    float s4 = wred[0][0][tid] + wred[1][0][tid] + wred[2][0][tid] + wred[3][0][tid];
    float q4 = wred[0][1][tid] + wred[1][1][tid] + wred[2][1][tid] + wred[3][1][tid];
    float* bkt = Sout + (blockIdx.x & (SBUK - 1)) * 256;
    atomicAdd(&bkt[tid], s4);
    atomicAdd(&bkt[DD + tid], q4);
  }
}

// ------- final: h += relu(bn3(relu(bn2(z)))); both BN params in-prologue -------

__global__ __launch_bounds__(256) void k_final(
    const unsigned short* __restrict__ Z, const float* __restrict__ stats2,
    const float* __restrict__ g2, const float* __restrict__ b2v,
    const float* __restrict__ stats3, const float* __restrict__ g3,
    const float* __restrict__ b3v, float* __restrict__ H,
    unsigned short* __restrict__ hbout, int n8, float inv_n) {
  __shared__ float s2l[DD], h2l[DD], s3l[DD], h3l[DD];
  int tid = threadIdx.x;
  if (tid < DD) {
    float mu = bucket_sum(stats2, tid) * inv_n;
    float var = bucket_sum(stats2, DD + tid) * inv_n - mu * mu;
    float sc = g2[tid] * rsqrtf(var + BN_EPS);
    s2l[tid] = sc;
    h2l[tid] = fmaf(-mu, sc, b2v[tid]);
    mu = bucket_sum(stats3, tid) * inv_n;
    var = bucket_sum(stats3, DD + tid) * inv_n - mu * mu;
    sc = g3[tid] * rsqrtf(var + BN_EPS);
    s3l[tid] = sc;
    h3l[tid] = fmaf(-mu, sc, b3v[tid]);
  }
  __syncthreads();
  int c8 = tid & 15;
  float s2[8], h2[8], s3[8], h3[8];
#pragma unroll
  for (int j = 0; j < 8; ++j) {
    s2[j] = s2l[c8 * 8 + j]; h2[j] = h2l[c8 * 8 + j];
    s3[j] = s3l[c8 * 8 + j]; h3[j] = h3l[c8 * 8 + j];
  }
  for (int idx = blockIdx.x * 256 + tid; idx < n8; idx += gridDim.x * 256) {
    short8 z = ((const short8*)Z)[idx];
    float4 hv0 = ((const float4*)H)[idx * 2];
    float4 hv1 = ((const float4*)H)[idx * 2 + 1];
    float hv[8] = {hv0.x, hv0.y, hv0.z, hv0.w, hv1.x, hv1.y, hv1.z, hv1.w};
    float o[8];
    short8 ob;
#pragma unroll
    for (int j = 0; j < 8; ++j) {
      float a = fmaxf(fmaf(bf2f((unsigned short)z[j]), s2[j], h2[j]), 0.f);
      o[j] = hv[j] + fmaxf(fmaf(a, s3[j], h3[j]), 0.f);
      ob[j] = (short)f2bf(o[j]);
    }
    ((float4*)H)[idx * 2] = make_float4(o[0], o[1], o[2], o[3]);
    ((float4*)H)[idx * 2 + 1] = make_float4(o[4], o[5], o[6], o[7]);
    *(short8*)(hbout + (size_t)idx * 8) = ob;
  }
}

// ---------------- launch ----------------

extern "C" void kernel_launch(void* const* d_in, const int* in_sizes, int n_in,
                              void* d_out, int out_size, void* d_ws, size_t ws_size,
                              hipStream_t stream) {
  const float* h_in = (const float*)d_in[0];
  const int* src = (const int*)d_in[1];
  const int* dst = (const int*)d_in[2];
  const float* W_emb = (const float*)d_in[3];
  const float* b_emb = (const float*)d_in[4];
  const float* epsv = (const float*)d_in[5];
  const float* W1 = (const float*)d_in[6];
  const float* b1 = (const float*)d_in[7];
  const float* g1 = (const float*)d_in[8];
  const float* be1 = (const float*)d_in[9];
  const float* W2 = (const float*)d_in[10];
  const float* b2 = (const float*)d_in[11];
  const float* ga = (const float*)d_in[12];
  const float* ba = (const float*)d_in[13];
  const float* gl = (const float*)d_in[14];
  const float* bl = (const float*)d_in[15];

  const int Nn = in_sizes[0] / DD;  // 50000
  const int E = in_sizes[1];        // 1600000
  const int nbuck = (Nn + 255) >> 8;
  const int gb = (Nn + 127) / 128;  // 128-row GEMM blocks

  char* ws = (char*)d_ws;
  size_t off = 0;
  auto alloc = [&](size_t bytes) -> void* {
    off = (off + 255) & ~(size_t)255;
    void* p = ws + off;
    off += bytes;
    return p;
  };
  int* ebuf = (int*)alloc((size_t)nbuck * CAP * 4);
  unsigned short* perm = (unsigned short*)alloc((size_t)nbuck * CAP * 2);
  // fill[256] + 12 bucketed stats buffers S (3/layer x SBUK x 256), one memset
  const size_t sbytes = (size_t)12 * SBUK * 256 * 4;
  int* fill = (int*)alloc(256 * 4 + sbytes);
  float* Sall = (float*)(fill + 256);
  int* row_beg = (int*)alloc((size_t)Nn * 4);
  int* row_end = (int*)alloc((size_t)Nn * 4);
  unsigned short* Wb = (unsigned short*)alloc((size_t)9 * WSTRIDE * 2);
  unsigned short* hb = (unsigned short*)alloc((size_t)Nn * DD * 2);
  unsigned short* xb = (unsigned short*)alloc((size_t)Nn * DD * 2);
  unsigned short* yb = (unsigned short*)alloc((size_t)Nn * DD * 2);
  float* h = (float*)d_out;  // fp32 h chain lives in d_out

  hipMemsetAsync(fill, 0, 256 * 4 + sbytes, stream);

  // CSR build (bucketed)
  int nblk1 = (E + CHUNK - 1) / CHUNK;
  k_scatter<<<nblk1, 256, 0, stream>>>(src, dst, fill, ebuf, E);
  k_csr<<<nbuck, 256, 0, stream>>>(fill, ebuf, perm, row_beg, row_end, Nn);

  // W pre-pack (bf16, B-fragment order)
  k_packW<<<(1 * WSTRIDE + 255) / 256, 256, 0, stream>>>(W_emb, Wb, 1);
  k_packW<<<(4 * WSTRIDE + 255) / 256, 256, 0, stream>>>(W1, Wb + WSTRIDE, 4);
  k_packW<<<(4 * WSTRIDE + 255) / 256, 256, 0, stream>>>(W2, Wb + (size_t)WSTRIDE * 5, 4);

  float inv_n = 1.0f / (float)Nn;
  int n8 = Nn * DD / 8;

  // embed: h = h_in @ W_emb + b_emb (fp32 h into d_out + bf16 mirror hb)
  k_gemm_mfma<false, false, true, true, true><<<gb, 256, 0, stream>>>(
      h_in, Wb, b_emb, nullptr, nullptr, nullptr, hb, h, nullptr, Nn, inv_n);

  for (int i = 0; i < NL; ++i) {
    float* S1 = Sall + (size_t)i * 3 * SBUK * 256;
    float* S2 = S1 + SBUK * 256;
    float* S3 = S2 + SBUK * 256;
    k_aggregate<<<(Nn + 3) / 4, 256, 0, stream>>>(hb, row_beg, row_end, perm, epsv, i,
                                                  xb, Nn);
    k_gemm_mfma<false, true, false, true, false><<<gb, 256, 0, stream>>>(
        xb, Wb + (size_t)WSTRIDE * (1 + i), b1 + i * DD, nullptr, nullptr, nullptr,
        yb, nullptr, S1, Nn, inv_n);
    k_gemm_mfma<true, true, false, true, false><<<gb, 256, 0, stream>>>(
        yb, Wb + (size_t)WSTRIDE * (5 + i), b2 + i * DD, S1, g1 + i * DD, be1 + i * DD,
        xb, nullptr, S2, Nn, inv_n);
    k_stats3<<<NST, 256, 0, stream>>>(xb, S2, ga + i * DD, ba + i * DD, S3, n8,
                                      inv_n);
    k_final<<<2048, 256, 0, stream>>>(xb, S2, ga + i * DD, ba + i * DD, S3, gl + i * DD,
                                      bl + i * DD, h, hb, n8, inv_n);
  }
}

// Round 11
// 523.088 us; speedup vs baseline: 1.2841x; 1.1158x over previous
//
#include <hip/hip_runtime.h>

#define DD 128
#define NL 4
#define BN_EPS 1e-5f
#define WSTRIDE 16384   // 128*128 bf16 elements per packed matrix
#define CAP 10240       // per-bucket edge capacity
#define CHUNK 8192      // edges per k_scatter block
#define NST 512         // k_stats3 grid
#define SBUK 16         // stat atomic buckets (contention = nblocks/SBUK)

typedef __attribute__((ext_vector_type(8))) short short8;
typedef __attribute__((ext_vector_type(4))) float f32x4;

__device__ inline float bf2f(unsigned short u) {
  unsigned int x = ((unsigned int)u) << 16;
  return __builtin_bit_cast(float, x);
}
__device__ inline unsigned short f2bf(float f) {
  unsigned int u = __builtin_bit_cast(unsigned int, f);
  unsigned int r = (u + 0x7fffu + ((u >> 16) & 1u)) >> 16;
  return (unsigned short)r;
}

// sum SBUK bucketed partials for entry tid (tid < 256 range covers sum+sumsq)
__device__ inline float bucket_sum(const float* __restrict__ S, int tid) {
  float a = 0.f;
#pragma unroll
  for (int b = 0; b < SBUK; ++b) a += S[b * 256 + tid];
  return a;
}

// ---------------- bucketed CSR build ----------------

__global__ __launch_bounds__(256) void k_scatter(const int* __restrict__ src,
                                                 const int* __restrict__ dst,
                                                 int* __restrict__ fill,
                                                 int* __restrict__ ebuf, int E) {
  __shared__ int hist[256], blkbase[256], cnt2[256];
  int tid = threadIdx.x;
  hist[tid] = 0;
  cnt2[tid] = 0;
  __syncthreads();
  int base = blockIdx.x * CHUNK;
  int cnt = min(CHUNK, E - base);
  for (int i = tid; i < cnt; i += 256) atomicAdd(&hist[dst[base + i] >> 8], 1);
  __syncthreads();
  int h = hist[tid];
  if (h > 0) blkbase[tid] = atomicAdd(&fill[tid], h);
  __syncthreads();
  for (int i = tid; i < cnt; i += 256) {
    int d = dst[base + i];
    int b = d >> 8;
    int off = blkbase[b] + atomicAdd(&cnt2[b], 1);
    if (off < CAP) ebuf[b * CAP + off] = ((d & 255) << 16) | src[base + i];
  }
}

// simple per-row distribute (src-sort measured null for locality -> removed)

__global__ __launch_bounds__(256) void k_csr(const int* __restrict__ fill,
                                             const int* __restrict__ ebuf,
                                             unsigned short* __restrict__ perm,
                                             int* __restrict__ row_beg,
                                             int* __restrict__ row_end, int n) {
  __shared__ int ncnt[256], lstart[256], cnt2[256], s[256];
  int tid = threadIdx.x;
  int b = blockIdx.x;
  ncnt[tid] = 0;
  cnt2[tid] = 0;
  __syncthreads();
  int cnt = min(fill[b], CAP);
  int base = b * CAP;
  for (int i = tid; i < cnt; i += 256) atomicAdd(&ncnt[ebuf[base + i] >> 16], 1);
  __syncthreads();
  int v = ncnt[tid];
  s[tid] = v;
  __syncthreads();
  for (int off = 1; off < 256; off <<= 1) {
    int x = (tid >= off) ? s[tid - off] : 0;
    __syncthreads();
    s[tid] += x;
    __syncthreads();
  }
  int st = s[tid] - v;
  lstart[tid] = st;
  int node = b * 256 + tid;
  if (node < n) {
    row_beg[node] = base + st;
    row_end[node] = base + st + v;
  }
  __syncthreads();
  for (int i = tid; i < cnt; i += 256) {
    int e = ebuf[base + i];
    int l = e >> 16;
    int pos = lstart[l] + atomicAdd(&cnt2[l], 1);
    perm[base + pos] = (unsigned short)(e & 0xFFFF);
  }
}

// ---------------- W pre-pack ----------------

__global__ void k_packW(const float* __restrict__ W, unsigned short* __restrict__ out,
                        int nmat) {
  int idx = blockIdx.x * 256 + threadIdx.x;
  int m = idx >> 14;
  if (m >= nmat) return;
  int o = idx & (WSTRIDE - 1);
  int frag = o >> 9;
  int l = (o >> 3) & 63;
  int j = o & 7;
  int t = frag >> 2, s = frag & 3;
  int k = s * 32 + ((l >> 4) << 3) + j;
  int n = (t << 4) + (l & 15);
  out[(size_t)m * WSTRIDE + o] = f2bf(W[(size_t)m * (DD * DD) + k * DD + n]);
}

// ---------------- GIN aggregation (pull, bucketed CSR, bf16 rows) ----------------
// Measured floor (48.8us): 1 node/wave, 12500 blocks, 8-deep unroll + 4/2/1 tail.

__global__ __launch_bounds__(256) void k_aggregate(
    const unsigned short* __restrict__ hb, const int* __restrict__ row_beg,
    const int* __restrict__ row_end, const unsigned short* __restrict__ perm,
    const float* __restrict__ epsv, int layer, unsigned short* __restrict__ xout,
    int n) {
  int wv = (blockIdx.x * 256 + threadIdx.x) >> 6;
  if (wv >= n) return;
  int lane = threadIdx.x & 63;
  int sub = lane >> 4;
  int c8 = lane & 15;
  int beg = row_beg[wv], end = row_end[wv];
  float acc[8] = {0.f, 0.f, 0.f, 0.f, 0.f, 0.f, 0.f, 0.f};
  const unsigned short* hbc = hb + c8 * 8;
  int e = beg + sub;
  for (; e + 28 < end; e += 32) {
    int s0 = perm[e];
    int s1 = perm[e + 4];
    int s2 = perm[e + 8];
    int s3 = perm[e + 12];
    int s4 = perm[e + 16];
    int s5 = perm[e + 20];
    int s6 = perm[e + 24];
    int s7 = perm[e + 28];
    short8 v0 = *(const short8*)(hbc + (size_t)s0 * DD);
    short8 v1 = *(const short8*)(hbc + (size_t)s1 * DD);
    short8 v2 = *(const short8*)(hbc + (size_t)s2 * DD);
    short8 v3 = *(const short8*)(hbc + (size_t)s3 * DD);
    short8 v4 = *(const short8*)(hbc + (size_t)s4 * DD);
    short8 v5 = *(const short8*)(hbc + (size_t)s5 * DD);
    short8 v6 = *(const short8*)(hbc + (size_t)s6 * DD);
    short8 v7 = *(const short8*)(hbc + (size_t)s7 * DD);
#pragma unroll
    for (int j = 0; j < 8; ++j) {
      float t0 = bf2f((unsigned short)v0[j]) + bf2f((unsigned short)v1[j]);
      float t1 = bf2f((unsigned short)v2[j]) + bf2f((unsigned short)v3[j]);
      float t2 = bf2f((unsigned short)v4[j]) + bf2f((unsigned short)v5[j]);
      float t3 = bf2f((unsigned short)v6[j]) + bf2f((unsigned short)v7[j]);
      acc[j] += (t0 + t1) + (t2 + t3);
    }
  }
  if (e + 12 < end) {
    int s0 = perm[e];
    int s1 = perm[e + 4];
    int s2 = perm[e + 8];
    int s3 = perm[e + 12];
    short8 v0 = *(const short8*)(hbc + (size_t)s0 * DD);
    short8 v1 = *(const short8*)(hbc + (size_t)s1 * DD);
    short8 v2 = *(const short8*)(hbc + (size_t)s2 * DD);
    short8 v3 = *(const short8*)(hbc + (size_t)s3 * DD);
#pragma unroll
    for (int j = 0; j < 8; ++j) {
      acc[j] += (bf2f((unsigned short)v0[j]) + bf2f((unsigned short)v1[j])) +
                (bf2f((unsigned short)v2[j]) + bf2f((unsigned short)v3[j]));
    }
    e += 16;
  }
  if (e + 4 < end) {
    int s0 = perm[e];
    int s1 = perm[e + 4];
    short8 v0 = *(const short8*)(hbc + (size_t)s0 * DD);
    short8 v1 = *(const short8*)(hbc + (size_t)s1 * DD);
#pragma unroll
    for (int j = 0; j < 8; ++j)
      acc[j] += bf2f((unsigned short)v0[j]) + bf2f((unsigned short)v1[j]);
    e += 8;
  }
  if (e < end) {
    int s0 = perm[e];
    short8 v0 = *(const short8*)(hbc + (size_t)s0 * DD);
#pragma unroll
    for (int j = 0; j < 8; ++j) acc[j] += bf2f((unsigned short)v0[j]);
  }
#pragma unroll
  for (int j = 0; j < 8; ++j) {
    acc[j] += __shfl_xor(acc[j], 16);
    acc[j] += __shfl_xor(acc[j], 32);
  }
  if (sub == 0) {
    float ep = 1.0f + epsv[layer];
    short8 hv = *(const short8*)(hb + (size_t)wv * DD + c8 * 8);
    short8 o;
#pragma unroll
    for (int j = 0; j < 8; ++j)
      o[j] = (short)f2bf(fmaf(ep, bf2f((unsigned short)hv[j]), acc[j]));
    *(short8*)(xout + (size_t)wv * DD + c8 * 8) = o;
  }
}

// ---------------- bf16 MFMA GEMM [nrows,128] x [128,128] + bias ----------------
// 64-row blocks (128-row variant measured -43us: VGPR/occupancy + tail quant).
// W staged in LDS; PRE relu-bn on A-load; STATS bucketed atomics.

template <bool PRE, bool STATS, bool IN_F32, bool OUT_BF16, bool OUT_F32>
__global__ __launch_bounds__(256) void k_gemm_mfma(
    const void* __restrict__ Xv, const unsigned short* __restrict__ Wb,
    const float* __restrict__ bias, const float* __restrict__ statsPre,
    const float* __restrict__ gPre, const float* __restrict__ bPre,
    unsigned short* __restrict__ Yb, float* __restrict__ Yf,
    float* __restrict__ Sout, int nrows, float inv_n) {
  __shared__ short8 Wl[2048];      // 32KB packed W
  __shared__ float red[4][2][DD];  // [wave][sum/sumsq][col]
  __shared__ float s_sc[DD], s_sh[DD];
  int tid = threadIdx.x;
  int wave = tid >> 6, lane = tid & 63;
  int quad = lane >> 4, n16 = lane & 15;
  int m0 = blockIdx.x * 64 + wave * 16;
  int rowA = m0 + n16;

  const short8* W8 = (const short8*)Wb;
#pragma unroll
  for (int i = 0; i < 8; ++i) Wl[i * 256 + tid] = W8[i * 256 + tid];

  if (PRE) {
    if (tid < DD) {
      float mu = bucket_sum(statsPre, tid) * inv_n;
      float var = bucket_sum(statsPre, DD + tid) * inv_n - mu * mu;
      float sc = gPre[tid] * rsqrtf(var + BN_EPS);
      s_sc[tid] = sc;
      s_sh[tid] = fmaf(-mu, sc, bPre[tid]);
    }
  }
  __syncthreads();

  f32x4 acc[8];
#pragma unroll
  for (int t = 0; t < 8; ++t) acc[t] = (f32x4){0.f, 0.f, 0.f, 0.f};

#pragma unroll
  for (int s = 0; s < 4; ++s) {
    int kbase = s * 32 + quad * 8;
    short8 a = {0, 0, 0, 0, 0, 0, 0, 0};
    if (rowA < nrows) {
      if (IN_F32) {
        const float* xp = (const float*)Xv + (size_t)rowA * DD + kbase;
        float4 v0 = ((const float4*)xp)[0];
        float4 v1 = ((const float4*)xp)[1];
        a[0] = (short)f2bf(v0.x); a[1] = (short)f2bf(v0.y);
        a[2] = (short)f2bf(v0.z); a[3] = (short)f2bf(v0.w);
        a[4] = (short)f2bf(v1.x); a[5] = (short)f2bf(v1.y);
        a[6] = (short)f2bf(v1.z); a[7] = (short)f2bf(v1.w);
      } else {
        a = *(const short8*)((const unsigned short*)Xv + (size_t)rowA * DD + kbase);
        if (PRE) {
#pragma unroll
          for (int j = 0; j < 8; ++j) {
            float v = bf2f((unsigned short)a[j]);
            v = fmaxf(fmaf(v, s_sc[kbase + j], s_sh[kbase + j]), 0.f);
            a[j] = (short)f2bf(v);
          }
        }
      }
    }
#pragma unroll
    for (int t = 0; t < 8; ++t) {
      short8 b = Wl[(t * 4 + s) * 64 + lane];
      acc[t] = __builtin_amdgcn_mfma_f32_16x16x32_bf16(a, b, acc[t], 0, 0, 0);
    }
  }

#pragma unroll
  for (int t = 0; t < 8; ++t) {
    int col = t * 16 + n16;
    float bv = bias[col];
    float s_c = 0.f, q_c = 0.f;
#pragma unroll
    for (int r = 0; r < 4; ++r) {
      int row = m0 + quad * 4 + r;
      if (row < nrows) {
        float v = acc[t][r] + bv;
        if (OUT_BF16) Yb[(size_t)row * DD + col] = f2bf(v);
        if (OUT_F32) Yf[(size_t)row * DD + col] = v;
        if (STATS) { s_c += v; q_c += v * v; }
      }
    }
    if (STATS) {
      s_c += __shfl_xor(s_c, 16);
      q_c += __shfl_xor(q_c, 16);
      s_c += __shfl_xor(s_c, 32);
      q_c += __shfl_xor(q_c, 32);
      if (quad == 0) {  // lanes 0..15: one writer per (wave,col)
        red[wave][0][col] = s_c;
        red[wave][1][col] = q_c;
      }
    }
  }
  if (STATS) {
    __syncthreads();
    if (tid < DD) {
      float s4 = red[0][0][tid] + red[1][0][tid] + red[2][0][tid] + red[3][0][tid];
      float q4 = red[0][1][tid] + red[1][1][tid] + red[2][1][tid] + red[3][1][tid];
      float* bkt = Sout + (blockIdx.x & (SBUK - 1)) * 256;
      atomicAdd(&bkt[tid], s4);
      atomicAdd(&bkt[DD + tid], q4);
    }
  }
}

// ------- stats of a = relu(bn2(z)), z bf16; bucketed atomic accumulation -------

__global__ __launch_bounds__(256) void k_stats3(const unsigned short* __restrict__ Z,
                                                const float* __restrict__ stats2,
                                                const float* __restrict__ g2,
                                                const float* __restrict__ b2v,
                                                float* __restrict__ Sout, int n8,
                                                float inv_n) {
  __shared__ float wred[4][2][DD];
  __shared__ float s_sc[DD], s_sh[DD];
  int tid = threadIdx.x;
  if (tid < DD) {
    float mu = bucket_sum(stats2, tid) * inv_n;
    float var = bucket_sum(stats2, DD + tid) * inv_n - mu * mu;
    float sc = g2[tid] * rsqrtf(var + BN_EPS);
    s_sc[tid] = sc;
    s_sh[tid] = fmaf(-mu, sc, b2v[tid]);
  }
  __syncthreads();
  int c8 = tid & 15;
  int wave = tid >> 6, lane = tid & 63;
  float sc[8], sh[8];
#pragma unroll
  for (int j = 0; j < 8; ++j) { sc[j] = s_sc[c8 * 8 + j]; sh[j] = s_sh[c8 * 8 + j]; }
  float s[8] = {0, 0, 0, 0, 0, 0, 0, 0};
  float q[8] = {0, 0, 0, 0, 0, 0, 0, 0};
  for (int idx = blockIdx.x * 256 + tid; idx < n8; idx += gridDim.x * 256) {
    short8 z = ((const short8*)Z)[idx];
#pragma unroll
    for (int j = 0; j < 8; ++j) {
      float a = fmaxf(fmaf(bf2f((unsigned short)z[j]), sc[j], sh[j]), 0.f);
      s[j] += a;
      q[j] += a * a;
    }
  }
#pragma unroll
  for (int j = 0; j < 8; ++j) {  // combine lanes with equal c8 (xor 16, 32)
    s[j] += __shfl_xor(s[j], 16);
    q[j] += __shfl_xor(q[j], 16);
    s[j] += __shfl_xor(s[j], 32);
    q[j] += __shfl_xor(q[j], 32);
  }
  if (lane < 16) {
#pragma unroll
    for (int j = 0; j < 8; ++j) {
      wred[wave][0][lane * 8 + j] = s[j];
      wred[wave][1][lane * 8 + j] = q[j];
    }
  }
  __syncthreads();
  if (tid < DD) {
    float s4 = wred[0][0][tid] + wred[1][0][tid] + wred[2][0][tid] + wred[3][0][tid];
    float q4 = wred[0][1][tid] + wred[1][1][tid] + wred[2][1][tid] + wred[3][1][tid];
    float* bkt = Sout + (blockIdx.x & (SBUK - 1)) * 256;
    atomicAdd(&bkt[tid], s4);
    atomicAdd(&bkt[DD + tid], q4);
  }
}

// ------- final: h += relu(bn3(relu(bn2(z)))) with h kept ONLY in bf16 (hb) ------
// for layers 0..NL-2; LAST layer materializes fp32 h into d_out. Saves the
// fp32 H read+write (51.2 MB/layer) from the residual chain.

template <bool LAST>
__global__ __launch_bounds__(256) void k_final(
    const unsigned short* __restrict__ Z, const float* __restrict__ stats2,
    const float* __restrict__ g2, const float* __restrict__ b2v,
    const float* __restrict__ stats3, const float* __restrict__ g3,
    const float* __restrict__ b3v, const unsigned short* __restrict__ hbin,
    float* __restrict__ Hout, unsigned short* __restrict__ hbout, int n8,
    float inv_n) {
  __shared__ float s2l[DD], h2l[DD], s3l[DD], h3l[DD];
  int tid = threadIdx.x;
  if (tid < DD) {
    float mu = bucket_sum(stats2, tid) * inv_n;
    float var = bucket_sum(stats2, DD + tid) * inv_n - mu * mu;
    float sc = g2[tid] * rsqrtf(var + BN_EPS);
    s2l[tid] = sc;
    h2l[tid] = fmaf(-mu, sc, b2v[tid]);
    mu = bucket_sum(stats3, tid) * inv_n;
    var = bucket_sum(stats3, DD + tid) * inv_n - mu * mu;
    sc = g3[tid] * rsqrtf(var + BN_EPS);
    s3l[tid] = sc;
    h3l[tid] = fmaf(-mu, sc, b3v[tid]);
  }
  __syncthreads();
  int c8 = tid & 15;
  float s2[8], h2[8], s3[8], h3[8];
#pragma unroll
  for (int j = 0; j < 8; ++j) {
    s2[j] = s2l[c8 * 8 + j]; h2[j] = h2l[c8 * 8 + j];
    s3[j] = s3l[c8 * 8 + j]; h3[j] = h3l[c8 * 8 + j];
  }
  for (int idx = blockIdx.x * 256 + tid; idx < n8; idx += gridDim.x * 256) {
    short8 z = ((const short8*)Z)[idx];
    short8 hv = ((const short8*)hbin)[idx];
    float o[8];
#pragma unroll
    for (int j = 0; j < 8; ++j) {
      float a = fmaxf(fmaf(bf2f((unsigned short)z[j]), s2[j], h2[j]), 0.f);
      o[j] = bf2f((unsigned short)hv[j]) + fmaxf(fmaf(a, s3[j], h3[j]), 0.f);
    }
    if (LAST) {
      ((float4*)Hout)[idx * 2] = make_float4(o[0], o[1], o[2], o[3]);
      ((float4*)Hout)[idx * 2 + 1] = make_float4(o[4], o[5], o[6], o[7]);
    } else {
      short8 ob;
#pragma unroll
      for (int j = 0; j < 8; ++j) ob[j] = (short)f2bf(o[j]);
      ((short8*)hbout)[idx] = ob;
    }
  }
}

// ---------------- launch ----------------

extern "C" void kernel_launch(void* const* d_in, const int* in_sizes, int n_in,
                              void* d_out, int out_size, void* d_ws, size_t ws_size,
                              hipStream_t stream) {
  const float* h_in = (const float*)d_in[0];
  const int* src = (const int*)d_in[1];
  const int* dst = (const int*)d_in[2];
  const float* W_emb = (const float*)d_in[3];
  const float* b_emb = (const float*)d_in[4];
  const float* epsv = (const float*)d_in[5];
  const float* W1 = (const float*)d_in[6];
  const float* b1 = (const float*)d_in[7];
  const float* g1 = (const float*)d_in[8];
  const float* be1 = (const float*)d_in[9];
  const float* W2 = (const float*)d_in[10];
  const float* b2 = (const float*)d_in[11];
  const float* ga = (const float*)d_in[12];
  const float* ba = (const float*)d_in[13];
  const float* gl = (const float*)d_in[14];
  const float* bl = (const float*)d_in[15];

  const int Nn = in_sizes[0] / DD;  // 50000
  const int E = in_sizes[1];        // 1600000
  const int nbuck = (Nn + 255) >> 8;
  const int gb = (Nn + 63) / 64;

  char* ws = (char*)d_ws;
  size_t off = 0;
  auto alloc = [&](size_t bytes) -> void* {
    off = (off + 255) & ~(size_t)255;
    void* p = ws + off;
    off += bytes;
    return p;
  };
  int* ebuf = (int*)alloc((size_t)nbuck * CAP * 4);
  unsigned short* perm = (unsigned short*)alloc((size_t)nbuck * CAP * 2);
  // fill[256] + 12 bucketed stats buffers S (3/layer x SBUK x 256), one memset
  const size_t sbytes = (size_t)12 * SBUK * 256 * 4;
  int* fill = (int*)alloc(256 * 4 + sbytes);
  float* Sall = (float*)(fill + 256);
  int* row_beg = (int*)alloc((size_t)Nn * 4);
  int* row_end = (int*)alloc((size_t)Nn * 4);
  unsigned short* Wb = (unsigned short*)alloc((size_t)9 * WSTRIDE * 2);
  unsigned short* hb = (unsigned short*)alloc((size_t)Nn * DD * 2);
  unsigned short* xb = (unsigned short*)alloc((size_t)Nn * DD * 2);
  unsigned short* yb = (unsigned short*)alloc((size_t)Nn * DD * 2);
  float* h = (float*)d_out;  // fp32 h written ONLY by the last k_final

  hipMemsetAsync(fill, 0, 256 * 4 + sbytes, stream);

  // CSR build (bucketed)
  int nblk1 = (E + CHUNK - 1) / CHUNK;
  k_scatter<<<nblk1, 256, 0, stream>>>(src, dst, fill, ebuf, E);
  k_csr<<<nbuck, 256, 0, stream>>>(fill, ebuf, perm, row_beg, row_end, Nn);

  // W pre-pack (bf16, B-fragment order)
  k_packW<<<(1 * WSTRIDE + 255) / 256, 256, 0, stream>>>(W_emb, Wb, 1);
  k_packW<<<(4 * WSTRIDE + 255) / 256, 256, 0, stream>>>(W1, Wb + WSTRIDE, 4);
  k_packW<<<(4 * WSTRIDE + 255) / 256, 256, 0, stream>>>(W2, Wb + (size_t)WSTRIDE * 5, 4);

  float inv_n = 1.0f / (float)Nn;
  int n8 = Nn * DD / 8;

  // embed: hb = bf16(h_in @ W_emb + b_emb)  (no fp32 H write)
  k_gemm_mfma<false, false, true, true, false><<<gb, 256, 0, stream>>>(
      h_in, Wb, b_emb, nullptr, nullptr, nullptr, hb, nullptr, nullptr, Nn, inv_n);

  for (int i = 0; i < NL; ++i) {
    float* S1 = Sall + (size_t)i * 3 * SBUK * 256;
    float* S2 = S1 + SBUK * 256;
    float* S3 = S2 + SBUK * 256;
    k_aggregate<<<(Nn + 3) / 4, 256, 0, stream>>>(hb, row_beg, row_end, perm, epsv, i,
                                                  xb, Nn);
    k_gemm_mfma<false, true, false, true, false><<<gb, 256, 0, stream>>>(
        xb, Wb + (size_t)WSTRIDE * (1 + i), b1 + i * DD, nullptr, nullptr, nullptr,
        yb, nullptr, S1, Nn, inv_n);
    k_gemm_mfma<true, true, false, true, false><<<gb, 256, 0, stream>>>(
        yb, Wb + (size_t)WSTRIDE * (5 + i), b2 + i * DD, S1, g1 + i * DD, be1 + i * DD,
        xb, nullptr, S2, Nn, inv_n);
    k_stats3<<<NST, 256, 0, stream>>>(xb, S2, ga + i * DD, ba + i * DD, S3, n8,
                                      inv_n);
    if (i < NL - 1) {
      k_final<false><<<2048, 256, 0, stream>>>(xb, S2, ga + i * DD, ba + i * DD, S3,
                                               gl + i * DD, bl + i * DD, hb, nullptr,
                                               hb, n8, inv_n);
    } else {
      k_final<true><<<2048, 256, 0, stream>>>(xb, S2, ga + i * DD, ba + i * DD, S3,
                                              gl + i * DD, bl + i * DD, hb, h,
                                              nullptr, n8, inv_n);
    }
  }
}